// Round 13
// baseline (451.596 us; speedup 1.0000x reference)
//
#include <hip/hip_runtime.h>
#include <cstdint>
#include <cstddef>

#define FDIM 128
#define CHUNK 4096   // edges per binning chunk
#define BSHIFT 8     // 256 nodes per bucket
#define BMASK 255
#define MAXB 512     // max buckets supported (N <= 131072)

typedef unsigned short ushort_t;
typedef __attribute__((ext_vector_type(8))) short short8;   // 8 bf16 (4 VGPRs)
typedef __attribute__((ext_vector_type(4))) float floatx4;  // MFMA C/D

// bf16 helpers (bit-level, RTN-even).
__device__ inline ushort_t f2bf(float f) {
  unsigned u = __float_as_uint(f);
  u += 0x7fffu + ((u >> 16) & 1u);
  return (ushort_t)(u >> 16);
}
__device__ inline float bf2f(ushort_t h) {
  return __uint_as_float((unsigned)h << 16);
}

// ---------------- CSR build (bucketed) ----------------
// k_histw: blocks [0,NCH) = per-chunk dst-bucket histogram; blocks
// [NCH,NCH+3) = W prep (fused). Block NCH also zeroes the bump counter.
__global__ __launch_bounds__(256) void k_histw(const int* __restrict__ dst, int e,
                                               int nb, int* __restrict__ chunkHist,
                                               int nch,
                                               const float* __restrict__ W1,
                                               const float* __restrict__ W2,
                                               const float* __restrict__ W3,
                                               ushort_t* __restrict__ wsw,
                                               int* __restrict__ counter) {
  if (blockIdx.x >= (unsigned)nch) {
    int b = blockIdx.x - nch;
    if (b == 0 && threadIdx.x == 0) *counter = 0;  // for scan1's atomic bump
    // W prep: fp32 -> bf16, B-fragment order. Frag slot (ct, n=lane&15)
    // holds TRUE column (lane&15)*8+ct -> coalesced uint4 C-stores in k_mm.
    const float* W = (b == 0) ? W1 : (b == 1) ? W2 : W3;
    ushort_t* o = wsw + (size_t)b * 16384;
    for (int idx = threadIdx.x; idx < 16384; idx += 256) {
      int j = idx & 7;
      int lane = (idx >> 3) & 63;
      int ct = (idx >> 9) & 7;
      int kc = idx >> 12;
      int k = kc * 32 + (lane >> 4) * 8 + j;
      int col = (lane & 15) * 8 + ct;
      o[idx] = f2bf(W[k * FDIM + col]);
    }
    return;
  }
  __shared__ int h[MAXB];
  int c = blockIdx.x;
  int base = c * CHUNK;
  int end = min(base + CHUNK, e);
  for (int i = threadIdx.x; i < nb; i += 256) h[i] = 0;
  __syncthreads();
  for (int i = base + threadIdx.x; i < end; i += 256)
    atomicAdd(&h[dst[i] >> BSHIFT], 1);
  __syncthreads();
  for (int b = threadIdx.x; b < nb; b += 256)
    chunkHist[(size_t)c * nb + b] = h[b];
}

// Per-bucket scan over the chunk axis; bucket base atomic-bump allocated
// (disjoint segments, order-free; kills k_scan2).
__global__ __launch_bounds__(512) void k_scan1(const int* __restrict__ chunkHist,
                                               int nchunks, int nb,
                                               int* __restrict__ chunkOff,
                                               int* __restrict__ bucketTotal,
                                               int* __restrict__ bucketBase,
                                               int* __restrict__ counter) {
  __shared__ int sb[512];
  int b = blockIdx.x;
  int t = threadIdx.x;
  int base = 0;
  for (int c0 = 0; c0 < nchunks; c0 += 512) {
    int c = c0 + t;
    int v = (c < nchunks) ? chunkHist[(size_t)c * nb + b] : 0;
    int x = v;
    sb[t] = x;
    __syncthreads();
    for (int off = 1; off < 512; off <<= 1) {
      int y = (t >= off) ? sb[t - off] : 0;
      __syncthreads();
      x += y;
      sb[t] = x;
      __syncthreads();
    }
    if (c < nchunks) chunkOff[(size_t)c * nb + b] = base + x - v;
    int tileTot = sb[511];
    __syncthreads();
    base += tileTot;
  }
  if (t == 0) {
    bucketTotal[b] = base;
    bucketBase[b] = atomicAdd(counter, base);
  }
}

__global__ __launch_bounds__(256) void k_bin(const int* __restrict__ src,
                                             const int* __restrict__ dst, int e, int nb,
                                             const int* __restrict__ chunkHist,
                                             const int* __restrict__ chunkOff,
                                             const int* __restrict__ bucketBase,
                                             unsigned* __restrict__ binned) {
  __shared__ unsigned sortedL[CHUNK];
  __shared__ int gtarget[CHUNK];
  __shared__ int lbase[MAXB], lcur[MAXB], gbase[MAXB];
  __shared__ int stmp[256];
  int c = blockIdx.x;
  int base = c * CHUNK;
  int end = min(base + CHUNK, e);
  for (int i = threadIdx.x; i < nb; i += 256) {
    lbase[i] = chunkHist[(size_t)c * nb + i];  // temp: counts
    gbase[i] = bucketBase[i] + chunkOff[(size_t)c * nb + i];
  }
  __syncthreads();
  int carry = 0;
  for (int i0 = 0; i0 < nb; i0 += 256) {
    int i = i0 + threadIdx.x;
    int v = (i < nb) ? lbase[i] : 0;
    int x = v;
    stmp[threadIdx.x] = x;
    __syncthreads();
    for (int off = 1; off < 256; off <<= 1) {
      int y = (threadIdx.x >= off) ? stmp[threadIdx.x - off] : 0;
      __syncthreads();
      x += y;
      stmp[threadIdx.x] = x;
      __syncthreads();
    }
    if (i < nb) lbase[i] = carry + x - v;
    int tileTot = stmp[255];
    __syncthreads();
    carry += tileTot;
  }
  for (int i = threadIdx.x; i < nb; i += 256) lcur[i] = lbase[i];
  __syncthreads();
  for (int i = base + threadIdx.x; i < end; i += 256) {
    int d = dst[i];
    int sv = src[i];
    int b = d >> BSHIFT;
    int slot = atomicAdd(&lcur[b], 1);
    sortedL[slot] = ((unsigned)sv << BSHIFT) | (unsigned)(d & BMASK);
    gtarget[slot] = gbase[b] + (slot - lbase[b]);
  }
  __syncthreads();
  for (int i = threadIdx.x; i < end - base; i += 256)
    binned[gtarget[i]] = sortedL[i];
}

// One block per bucket: per-node CSR rows in the bucket's private window.
// colPacked written as src only; the fused edgew pass ORs in the bf15 weight.
__global__ __launch_bounds__(256) void k_fill2(const unsigned* __restrict__ binned,
                                               const int* __restrict__ bucketBase,
                                               const int* __restrict__ bucketTotal,
                                               int n,
                                               int* __restrict__ rowStart,
                                               int* __restrict__ deg,
                                               float* __restrict__ dis,
                                               unsigned* __restrict__ colPacked) {
  __shared__ int h[256], sb[256], cur[256];
  int b = blockIdx.x;
  int s0 = bucketBase[b], s1 = s0 + bucketTotal[b];
  int nodeBase = b << BSHIFT;
  int t = threadIdx.x;
  h[t] = 0;
  __syncthreads();
  for (int i = s0 + t; i < s1; i += 256) atomicAdd(&h[binned[i] & BMASK], 1);
  __syncthreads();
  int v = h[t];
  int x = v;
  sb[t] = x;
  __syncthreads();
  for (int off = 1; off < 256; off <<= 1) {
    int y = (t >= off) ? sb[t - off] : 0;
    __syncthreads();
    x += y;
    sb[t] = x;
    __syncthreads();
  }
  int start = s0 + x - v;
  cur[t] = start;
  int node = nodeBase + t;
  if (node < n) {
    rowStart[node] = start;
    deg[node] = v;
    dis[node] = rsqrtf((float)(v + 1));  // +1 self-loop
  }
  __syncthreads();
  for (int i = s0 + t; i < s1; i += 256) {
    unsigned en = binned[i];
    int slot = atomicAdd(&cur[en & BMASK], 1);
    colPacked[slot] = en >> BSHIFT;  // src (< 2^17); weight ORed in later
  }
}

// ---------------- MFMA matmul (row-major H) ----------
// Blocks [0,mmb) = matmul; blocks [mmb,..) (EDGW=1, first layer only) pack
// the edge weight: colPacked[i] |= bf16(dis[src])<<17.
template <int INBF, int EDGW>
__global__ __launch_bounds__(256) void k_mm(const void* __restrict__ Ain,
                                            const ushort_t* __restrict__ Wsw,
                                            ushort_t* __restrict__ O, int n, int mmb,
                                            unsigned* __restrict__ colPacked, int e,
                                            const float* __restrict__ dis) {
  if (EDGW && blockIdx.x >= (unsigned)mmb) {
    int base = (blockIdx.x - mmb) * 2048 + threadIdx.x;
    for (int k = 0; k < 8; ++k) {
      int i = base + k * 256;
      if (i < e) {
        unsigned p = colPacked[i];  // pure src here
        colPacked[i] = p | ((unsigned)f2bf(dis[p]) << 17);
      }
    }
    return;
  }
  __shared__ ushort_t Bs[16384];  // 32 KB
  int tid = threadIdx.x;
  for (int q = tid; q < 2048; q += 256)
    ((uint4*)Bs)[q] = ((const uint4*)Wsw)[q];
  __syncthreads();

  int w = tid >> 6;
  int lane = tid & 63;
  int quad = lane >> 4;
  int l15 = lane & 15;
  int rb = blockIdx.x * 128 + w * 32;
  const float* Af = (const float*)Ain;
  const ushort_t* Ab = (const ushort_t*)Ain;

  int row0 = rb + l15;
  int row1 = rb + 16 + l15;
  bool v0 = row0 < n, v1 = row1 < n;

  floatx4 acc[2][8];
#pragma unroll
  for (int rt = 0; rt < 2; ++rt)
#pragma unroll
    for (int ct = 0; ct < 8; ++ct) acc[rt][ct] = floatx4{0.f, 0.f, 0.f, 0.f};

#pragma unroll
  for (int kc = 0; kc < 4; ++kc) {
    int k0 = kc * 32 + quad * 8;
    short8 a0 = short8{0, 0, 0, 0, 0, 0, 0, 0};
    short8 a1 = short8{0, 0, 0, 0, 0, 0, 0, 0};
    if (INBF) {
      if (v0) a0 = *(const short8*)&Ab[(size_t)row0 * FDIM + k0];
      if (v1) a1 = *(const short8*)&Ab[(size_t)row1 * FDIM + k0];
    } else {
      if (v0) {
        float4 f0 = *(const float4*)&Af[(size_t)row0 * FDIM + k0];
        float4 f1 = *(const float4*)&Af[(size_t)row0 * FDIM + k0 + 4];
        a0 = short8{(short)f2bf(f0.x), (short)f2bf(f0.y), (short)f2bf(f0.z),
                    (short)f2bf(f0.w), (short)f2bf(f1.x), (short)f2bf(f1.y),
                    (short)f2bf(f1.z), (short)f2bf(f1.w)};
      }
      if (v1) {
        float4 f0 = *(const float4*)&Af[(size_t)row1 * FDIM + k0];
        float4 f1 = *(const float4*)&Af[(size_t)row1 * FDIM + k0 + 4];
        a1 = short8{(short)f2bf(f0.x), (short)f2bf(f0.y), (short)f2bf(f0.z),
                    (short)f2bf(f0.w), (short)f2bf(f1.x), (short)f2bf(f1.y),
                    (short)f2bf(f1.z), (short)f2bf(f1.w)};
      }
    }
#pragma unroll
    for (int ct = 0; ct < 8; ++ct) {
      short8 bf = *(const short8*)&Bs[((kc * 8 + ct) * 64 + lane) * 8];
      acc[0][ct] = __builtin_amdgcn_mfma_f32_16x16x32_bf16(a0, bf, acc[0][ct], 0, 0, 0);
      acc[1][ct] = __builtin_amdgcn_mfma_f32_16x16x32_bf16(a1, bf, acc[1][ct], 0, 0, 0);
    }
  }

#pragma unroll
  for (int rt = 0; rt < 2; ++rt) {
#pragma unroll
    for (int i = 0; i < 4; ++i) {
      int row = rb + rt * 16 + quad * 4 + i;
      if (row < n) {
        uint4 pk;
        pk.x = (unsigned)f2bf(acc[rt][0][i]) | ((unsigned)f2bf(acc[rt][1][i]) << 16);
        pk.y = (unsigned)f2bf(acc[rt][2][i]) | ((unsigned)f2bf(acc[rt][3][i]) << 16);
        pk.z = (unsigned)f2bf(acc[rt][4][i]) | ((unsigned)f2bf(acc[rt][5][i]) << 16);
        pk.w = (unsigned)f2bf(acc[rt][6][i]) | ((unsigned)f2bf(acc[rt][7][i]) << 16);
        *(uint4*)&O[(size_t)row * FDIM + l15 * 8] = pk;
      }
    }
  }
}

// ---------------- aggregation (pull) + bias + ReLU ------------------------
// 2 nodes per wave: 32 lanes x uint2 (8 B) = 256 B row; colPacked 4 B/edge.
// POOL=1 (layer 3): skip the Hout store entirely and reduce relu'd fp32 rows
// into pooled[graph] -- LDS partial per block (blocks are 8 consecutive
// nodes, ~99.5% single-graph since avg graph = 1562 nodes) + 128 global
// atomics; mixed-graph fallback = per-node atomics. Saves 25.6 MB write +
// 12.8 MB pool re-read + one dispatch; also drops one bf16 rounding of h3.
template <int POOL>
__global__ __launch_bounds__(256) void k_agg(const ushort_t* __restrict__ Hin,
                                             ushort_t* __restrict__ Hout,
                                             const int* __restrict__ rowStart,
                                             const int* __restrict__ degE,
                                             const unsigned* __restrict__ colPacked,
                                             const float* __restrict__ dis,
                                             const float* __restrict__ bias, int n,
                                             const int* __restrict__ batch,
                                             float* __restrict__ pooled) {
  __shared__ float pbuf[FDIM];
  __shared__ int guni;
  int t = threadIdx.x;
  int node = blockIdx.x * 8 + (t >> 5);
  int lane = t & 31;  // uint2 index within the 256 B row
  if (POOL) {
    if (t < FDIM) pbuf[t] = 0.f;
    if (t == 0) {
      int nb0 = blockIdx.x * 8;
      int nlast = min(nb0 + 7, n - 1);
      int g0 = batch[nb0];
      guni = (batch[nlast] == g0) ? g0 : -1;
    }
    __syncthreads();
  }
  bool active = node < n;
  float a0 = 0.f, a1 = 0.f, a2 = 0.f, a3 = 0.f;
  if (active) {
    const uint2* hin = (const uint2*)Hin;  // row stride 32 uint2
    float di = dis[node];
    uint2 su = hin[(size_t)node * 32 + lane];
    float wsl = di * di;
    a0 = wsl * __uint_as_float(su.x << 16);
    a1 = wsl * __uint_as_float(su.x & 0xffff0000u);
    a2 = wsl * __uint_as_float(su.y << 16);
    a3 = wsl * __uint_as_float(su.y & 0xffff0000u);
    int s0 = rowStart[node], cnt = degE[node];
#pragma unroll 4
    for (int j = 0; j < cnt; ++j) {
      unsigned pv = colPacked[s0 + j];
      int sidx = (int)(pv & 0x1ffffu);
      float wv = di * __uint_as_float((pv >> 17) << 16);
      uint2 u = hin[(size_t)sidx * 32 + lane];
      a0 += wv * __uint_as_float(u.x << 16);
      a1 += wv * __uint_as_float(u.x & 0xffff0000u);
      a2 += wv * __uint_as_float(u.y << 16);
      a3 += wv * __uint_as_float(u.y & 0xffff0000u);
    }
    float4 b = ((const float4*)bias)[lane];
    a0 = fmaxf(a0 + b.x, 0.f);
    a1 = fmaxf(a1 + b.y, 0.f);
    a2 = fmaxf(a2 + b.z, 0.f);
    a3 = fmaxf(a3 + b.w, 0.f);
  }
  if (!POOL) {
    if (active) {
      uint2 o;
      o.x = (unsigned)f2bf(a0) | ((unsigned)f2bf(a1) << 16);
      o.y = (unsigned)f2bf(a2) | ((unsigned)f2bf(a3) << 16);
      ((uint2*)Hout)[(size_t)node * 32 + lane] = o;
    }
    return;
  }
  // POOL epilogue
  if (active) {
    if (guni >= 0) {
      atomicAdd(&pbuf[lane * 4 + 0], a0);
      atomicAdd(&pbuf[lane * 4 + 1], a1);
      atomicAdd(&pbuf[lane * 4 + 2], a2);
      atomicAdd(&pbuf[lane * 4 + 3], a3);
    } else {
      int g = batch[node];
      atomicAdd(&pooled[(size_t)g * FDIM + lane * 4 + 0], a0);
      atomicAdd(&pooled[(size_t)g * FDIM + lane * 4 + 1], a1);
      atomicAdd(&pooled[(size_t)g * FDIM + lane * 4 + 2], a2);
      atomicAdd(&pooled[(size_t)g * FDIM + lane * 4 + 3], a3);
    }
  }
  __syncthreads();
  if (guni >= 0 && t < FDIM) atomicAdd(&pooled[(size_t)guni * FDIM + t], pbuf[t]);
}

// ---------------- classifier ----------------

__device__ inline int lower_bound_batch(const int* __restrict__ batch, int n, int g) {
  int lo = 0, hi = n;
  while (lo < hi) {
    int mid = (lo + hi) >> 1;
    if (batch[mid] < g) lo = mid + 1;
    else hi = mid;
  }
  return lo;
}

// One block per graph: mean + classify via wave shuffles.
__global__ __launch_bounds__(128) void k_final(const float* __restrict__ pooled,
                                               const int* __restrict__ batch, int n,
                                               const float* __restrict__ Wc,
                                               const float* __restrict__ bc,
                                               float* __restrict__ out, int g_count) {
  __shared__ int se[2];
  __shared__ float red[6];  // 2 waves x 3 classes
  int t = threadIdx.x;
  int g = blockIdx.x;
  if (t < 2) se[t] = lower_bound_batch(batch, n, g + t);
  __syncthreads();
  float inv = 1.0f / (float)max(se[1] - se[0], 1);
  float s = pooled[(size_t)g * FDIM + t] * inv;
#pragma unroll
  for (int c = 0; c < 3; ++c) {
    float v = s * Wc[t * 3 + c];
#pragma unroll
    for (int off = 1; off < 64; off <<= 1) v += __shfl_xor(v, off);
    if ((t & 63) == 0) red[(t >> 6) * 3 + c] = v;
  }
  __syncthreads();
  if (t < 3) out[g * 3 + t] = red[t] + red[3 + t] + bc[t];
}

// ---------------- host ----------------

extern "C" void kernel_launch(void* const* d_in, const int* in_sizes, int n_in,
                              void* d_out, int out_size, void* d_ws, size_t ws_size,
                              hipStream_t stream) {
  const float* x = (const float*)d_in[0];
  const int* edge = (const int*)d_in[1];
  const int* batch = (const int*)d_in[2];
  const float* W1 = (const float*)d_in[3];
  const float* b1 = (const float*)d_in[4];
  const float* W2 = (const float*)d_in[5];
  const float* b2 = (const float*)d_in[6];
  const float* W3 = (const float*)d_in[7];
  const float* b3 = (const float*)d_in[8];
  const float* Wc = (const float*)d_in[9];
  const float* bc = (const float*)d_in[10];
  float* out = (float*)d_out;

  const int N = in_sizes[0] / FDIM;
  const int E = in_sizes[1] / 2;
  const int G = out_size / 3;
  const int* src = edge;
  const int* dst = edge + E;

  const int NCH = (E + CHUNK - 1) / CHUNK;
  const int NB = (N + (1 << BSHIFT) - 1) >> BSHIFT;

  char* ws = (char*)d_ws;
  size_t off = 0;
  auto carve = [&](size_t bytes) -> void* {
    void* p = ws + off;
    off = (off + bytes + 255) & ~(size_t)255;
    return p;
  };
  ushort_t* h0 = (ushort_t*)carve((size_t)N * FDIM * 2);  // row-major bf16
  ushort_t* h1 = (ushort_t*)carve((size_t)N * FDIM * 2);
  unsigned* colPacked = (unsigned*)carve((size_t)E * 4);
  unsigned* binned = (unsigned*)carve((size_t)E * 4);
  int* chunkHist = (int*)carve((size_t)NCH * NB * 4);
  int* chunkOff = (int*)carve((size_t)NCH * NB * 4);
  int* bucketTotal = (int*)carve((size_t)NB * 4);
  int* bucketBase = (int*)carve((size_t)NB * 4);
  int* counter = (int*)carve(256);
  int* rowStart = (int*)carve((size_t)N * 4);
  int* deg = (int*)carve((size_t)N * 4);
  float* dis = (float*)carve((size_t)N * 4);
  float* pooled = (float*)carve((size_t)G * FDIM * 4);
  ushort_t* wsw = (ushort_t*)carve((size_t)3 * 16384 * 2);  // swizzled bf16 W
  (void)n_in;
  (void)ws_size;

  hipMemsetAsync(pooled, 0, (size_t)G * FDIM * 4, stream);

  k_histw<<<NCH + 3, 256, 0, stream>>>(dst, E, NB, chunkHist, NCH, W1, W2, W3, wsw,
                                       counter);
  k_scan1<<<NB, 512, 0, stream>>>(chunkHist, NCH, NB, chunkOff, bucketTotal,
                                  bucketBase, counter);
  k_bin<<<NCH, 256, 0, stream>>>(src, dst, E, NB, chunkHist, chunkOff, bucketBase,
                                 binned);
  k_fill2<<<NB, 256, 0, stream>>>(binned, bucketBase, bucketTotal, N, rowStart, deg,
                                  dis, colPacked);

  int mmb = (N + 127) / 128;
  int ewb = (E + 2047) / 2048;
  int aggb = (N + 7) / 8;
  k_mm<0, 1><<<mmb + ewb, 256, 0, stream>>>(x, wsw, h0, N, mmb, colPacked, E, dis);
  k_agg<0><<<aggb, 256, 0, stream>>>(h0, h1, rowStart, deg, colPacked, dis, b1, N,
                                     batch, nullptr);
  k_mm<1, 0><<<mmb, 256, 0, stream>>>(h1, wsw + 16384, h0, N, mmb, nullptr, 0,
                                      nullptr);
  k_agg<0><<<aggb, 256, 0, stream>>>(h0, h1, rowStart, deg, colPacked, dis, b2, N,
                                     batch, nullptr);
  k_mm<1, 0><<<mmb, 256, 0, stream>>>(h1, wsw + 32768, h0, N, mmb, nullptr, 0,
                                      nullptr);
  k_agg<1><<<aggb, 256, 0, stream>>>(h0, h1, rowStart, deg, colPacked, dis, b3, N,
                                     batch, pooled);

  k_final<<<G, 128, 0, stream>>>(pooled, batch, N, Wc, bc, out, G);
}

// Round 14
// 444.558 us; speedup vs baseline: 1.0158x; 1.0158x over previous
//
#include <hip/hip_runtime.h>
#include <cstdint>
#include <cstddef>

#define FDIM 128
#define CHUNK 4096   // edges per binning chunk
#define BSHIFT 8     // 256 nodes per bucket
#define BMASK 255
#define MAXB 512     // max buckets supported (N <= 131072)
#define NREP 32      // pooled-accumulator replicas (atomic contention / 32)

typedef unsigned short ushort_t;
typedef __attribute__((ext_vector_type(8))) short short8;   // 8 bf16 (4 VGPRs)
typedef __attribute__((ext_vector_type(4))) float floatx4;  // MFMA C/D

// bf16 helpers (bit-level, RTN-even).
__device__ inline ushort_t f2bf(float f) {
  unsigned u = __float_as_uint(f);
  u += 0x7fffu + ((u >> 16) & 1u);
  return (ushort_t)(u >> 16);
}
__device__ inline float bf2f(ushort_t h) {
  return __uint_as_float((unsigned)h << 16);
}

// ---------------- CSR build (bucketed) ----------------
// k_histw: blocks [0,NCH) = per-chunk dst-bucket histogram; blocks
// [NCH,NCH+3) = W prep (fused). Block NCH also zeroes the bump counter.
__global__ __launch_bounds__(256) void k_histw(const int* __restrict__ dst, int e,
                                               int nb, int* __restrict__ chunkHist,
                                               int nch,
                                               const float* __restrict__ W1,
                                               const float* __restrict__ W2,
                                               const float* __restrict__ W3,
                                               ushort_t* __restrict__ wsw,
                                               int* __restrict__ counter) {
  if (blockIdx.x >= (unsigned)nch) {
    int b = blockIdx.x - nch;
    if (b == 0 && threadIdx.x == 0) *counter = 0;  // for scan1's atomic bump
    // W prep: fp32 -> bf16, B-fragment order. Frag slot (ct, n=lane&15)
    // holds TRUE column (lane&15)*8+ct -> coalesced uint4 C-stores in k_mm.
    const float* W = (b == 0) ? W1 : (b == 1) ? W2 : W3;
    ushort_t* o = wsw + (size_t)b * 16384;
    for (int idx = threadIdx.x; idx < 16384; idx += 256) {
      int j = idx & 7;
      int lane = (idx >> 3) & 63;
      int ct = (idx >> 9) & 7;
      int kc = idx >> 12;
      int k = kc * 32 + (lane >> 4) * 8 + j;
      int col = (lane & 15) * 8 + ct;
      o[idx] = f2bf(W[k * FDIM + col]);
    }
    return;
  }
  __shared__ int h[MAXB];
  int c = blockIdx.x;
  int base = c * CHUNK;
  int end = min(base + CHUNK, e);
  for (int i = threadIdx.x; i < nb; i += 256) h[i] = 0;
  __syncthreads();
  for (int i = base + threadIdx.x; i < end; i += 256)
    atomicAdd(&h[dst[i] >> BSHIFT], 1);
  __syncthreads();
  for (int b = threadIdx.x; b < nb; b += 256)
    chunkHist[(size_t)c * nb + b] = h[b];
}

// Per-bucket scan over the chunk axis; bucket base atomic-bump allocated
// (disjoint segments, order-free; kills k_scan2).
__global__ __launch_bounds__(512) void k_scan1(const int* __restrict__ chunkHist,
                                               int nchunks, int nb,
                                               int* __restrict__ chunkOff,
                                               int* __restrict__ bucketTotal,
                                               int* __restrict__ bucketBase,
                                               int* __restrict__ counter) {
  __shared__ int sb[512];
  int b = blockIdx.x;
  int t = threadIdx.x;
  int base = 0;
  for (int c0 = 0; c0 < nchunks; c0 += 512) {
    int c = c0 + t;
    int v = (c < nchunks) ? chunkHist[(size_t)c * nb + b] : 0;
    int x = v;
    sb[t] = x;
    __syncthreads();
    for (int off = 1; off < 512; off <<= 1) {
      int y = (t >= off) ? sb[t - off] : 0;
      __syncthreads();
      x += y;
      sb[t] = x;
      __syncthreads();
    }
    if (c < nchunks) chunkOff[(size_t)c * nb + b] = base + x - v;
    int tileTot = sb[511];
    __syncthreads();
    base += tileTot;
  }
  if (t == 0) {
    bucketTotal[b] = base;
    bucketBase[b] = atomicAdd(counter, base);
  }
}

__global__ __launch_bounds__(256) void k_bin(const int* __restrict__ src,
                                             const int* __restrict__ dst, int e, int nb,
                                             const int* __restrict__ chunkHist,
                                             const int* __restrict__ chunkOff,
                                             const int* __restrict__ bucketBase,
                                             unsigned* __restrict__ binned) {
  __shared__ unsigned sortedL[CHUNK];
  __shared__ int gtarget[CHUNK];
  __shared__ int lbase[MAXB], lcur[MAXB], gbase[MAXB];
  __shared__ int stmp[256];
  int c = blockIdx.x;
  int base = c * CHUNK;
  int end = min(base + CHUNK, e);
  for (int i = threadIdx.x; i < nb; i += 256) {
    lbase[i] = chunkHist[(size_t)c * nb + i];  // temp: counts
    gbase[i] = bucketBase[i] + chunkOff[(size_t)c * nb + i];
  }
  __syncthreads();
  int carry = 0;
  for (int i0 = 0; i0 < nb; i0 += 256) {
    int i = i0 + threadIdx.x;
    int v = (i < nb) ? lbase[i] : 0;
    int x = v;
    stmp[threadIdx.x] = x;
    __syncthreads();
    for (int off = 1; off < 256; off <<= 1) {
      int y = (threadIdx.x >= off) ? stmp[threadIdx.x - off] : 0;
      __syncthreads();
      x += y;
      stmp[threadIdx.x] = x;
      __syncthreads();
    }
    if (i < nb) lbase[i] = carry + x - v;
    int tileTot = stmp[255];
    __syncthreads();
    carry += tileTot;
  }
  for (int i = threadIdx.x; i < nb; i += 256) lcur[i] = lbase[i];
  __syncthreads();
  for (int i = base + threadIdx.x; i < end; i += 256) {
    int d = dst[i];
    int sv = src[i];
    int b = d >> BSHIFT;
    int slot = atomicAdd(&lcur[b], 1);
    sortedL[slot] = ((unsigned)sv << BSHIFT) | (unsigned)(d & BMASK);
    gtarget[slot] = gbase[b] + (slot - lbase[b]);
  }
  __syncthreads();
  for (int i = threadIdx.x; i < end - base; i += 256)
    binned[gtarget[i]] = sortedL[i];
}

// One block per bucket: per-node CSR rows in the bucket's private window.
// colPacked written as src only; the fused edgew pass ORs in the bf15 weight.
__global__ __launch_bounds__(256) void k_fill2(const unsigned* __restrict__ binned,
                                               const int* __restrict__ bucketBase,
                                               const int* __restrict__ bucketTotal,
                                               int n,
                                               int* __restrict__ rowStart,
                                               int* __restrict__ deg,
                                               float* __restrict__ dis,
                                               unsigned* __restrict__ colPacked) {
  __shared__ int h[256], sb[256], cur[256];
  int b = blockIdx.x;
  int s0 = bucketBase[b], s1 = s0 + bucketTotal[b];
  int nodeBase = b << BSHIFT;
  int t = threadIdx.x;
  h[t] = 0;
  __syncthreads();
  for (int i = s0 + t; i < s1; i += 256) atomicAdd(&h[binned[i] & BMASK], 1);
  __syncthreads();
  int v = h[t];
  int x = v;
  sb[t] = x;
  __syncthreads();
  for (int off = 1; off < 256; off <<= 1) {
    int y = (t >= off) ? sb[t - off] : 0;
    __syncthreads();
    x += y;
    sb[t] = x;
    __syncthreads();
  }
  int start = s0 + x - v;
  cur[t] = start;
  int node = nodeBase + t;
  if (node < n) {
    rowStart[node] = start;
    deg[node] = v;
    dis[node] = rsqrtf((float)(v + 1));  // +1 self-loop
  }
  __syncthreads();
  for (int i = s0 + t; i < s1; i += 256) {
    unsigned en = binned[i];
    int slot = atomicAdd(&cur[en & BMASK], 1);
    colPacked[slot] = en >> BSHIFT;  // src (< 2^17); weight ORed in later
  }
}

// ---------------- MFMA matmul (row-major H) ----------
// Blocks [0,mmb) = matmul; blocks [mmb,..) (EDGW=1, first layer only) pack
// the edge weight: colPacked[i] |= bf16(dis[src])<<17.
template <int INBF, int EDGW>
__global__ __launch_bounds__(256) void k_mm(const void* __restrict__ Ain,
                                            const ushort_t* __restrict__ Wsw,
                                            ushort_t* __restrict__ O, int n, int mmb,
                                            unsigned* __restrict__ colPacked, int e,
                                            const float* __restrict__ dis) {
  if (EDGW && blockIdx.x >= (unsigned)mmb) {
    int base = (blockIdx.x - mmb) * 2048 + threadIdx.x;
    for (int k = 0; k < 8; ++k) {
      int i = base + k * 256;
      if (i < e) {
        unsigned p = colPacked[i];  // pure src here
        colPacked[i] = p | ((unsigned)f2bf(dis[p]) << 17);
      }
    }
    return;
  }
  __shared__ ushort_t Bs[16384];  // 32 KB
  int tid = threadIdx.x;
  for (int q = tid; q < 2048; q += 256)
    ((uint4*)Bs)[q] = ((const uint4*)Wsw)[q];
  __syncthreads();

  int w = tid >> 6;
  int lane = tid & 63;
  int quad = lane >> 4;
  int l15 = lane & 15;
  int rb = blockIdx.x * 128 + w * 32;
  const float* Af = (const float*)Ain;
  const ushort_t* Ab = (const ushort_t*)Ain;

  int row0 = rb + l15;
  int row1 = rb + 16 + l15;
  bool v0 = row0 < n, v1 = row1 < n;

  floatx4 acc[2][8];
#pragma unroll
  for (int rt = 0; rt < 2; ++rt)
#pragma unroll
    for (int ct = 0; ct < 8; ++ct) acc[rt][ct] = floatx4{0.f, 0.f, 0.f, 0.f};

#pragma unroll
  for (int kc = 0; kc < 4; ++kc) {
    int k0 = kc * 32 + quad * 8;
    short8 a0 = short8{0, 0, 0, 0, 0, 0, 0, 0};
    short8 a1 = short8{0, 0, 0, 0, 0, 0, 0, 0};
    if (INBF) {
      if (v0) a0 = *(const short8*)&Ab[(size_t)row0 * FDIM + k0];
      if (v1) a1 = *(const short8*)&Ab[(size_t)row1 * FDIM + k0];
    } else {
      if (v0) {
        float4 f0 = *(const float4*)&Af[(size_t)row0 * FDIM + k0];
        float4 f1 = *(const float4*)&Af[(size_t)row0 * FDIM + k0 + 4];
        a0 = short8{(short)f2bf(f0.x), (short)f2bf(f0.y), (short)f2bf(f0.z),
                    (short)f2bf(f0.w), (short)f2bf(f1.x), (short)f2bf(f1.y),
                    (short)f2bf(f1.z), (short)f2bf(f1.w)};
      }
      if (v1) {
        float4 f0 = *(const float4*)&Af[(size_t)row1 * FDIM + k0];
        float4 f1 = *(const float4*)&Af[(size_t)row1 * FDIM + k0 + 4];
        a1 = short8{(short)f2bf(f0.x), (short)f2bf(f0.y), (short)f2bf(f0.z),
                    (short)f2bf(f0.w), (short)f2bf(f1.x), (short)f2bf(f1.y),
                    (short)f2bf(f1.z), (short)f2bf(f1.w)};
      }
    }
#pragma unroll
    for (int ct = 0; ct < 8; ++ct) {
      short8 bf = *(const short8*)&Bs[((kc * 8 + ct) * 64 + lane) * 8];
      acc[0][ct] = __builtin_amdgcn_mfma_f32_16x16x32_bf16(a0, bf, acc[0][ct], 0, 0, 0);
      acc[1][ct] = __builtin_amdgcn_mfma_f32_16x16x32_bf16(a1, bf, acc[1][ct], 0, 0, 0);
    }
  }

#pragma unroll
  for (int rt = 0; rt < 2; ++rt) {
#pragma unroll
    for (int i = 0; i < 4; ++i) {
      int row = rb + rt * 16 + quad * 4 + i;
      if (row < n) {
        uint4 pk;
        pk.x = (unsigned)f2bf(acc[rt][0][i]) | ((unsigned)f2bf(acc[rt][1][i]) << 16);
        pk.y = (unsigned)f2bf(acc[rt][2][i]) | ((unsigned)f2bf(acc[rt][3][i]) << 16);
        pk.z = (unsigned)f2bf(acc[rt][4][i]) | ((unsigned)f2bf(acc[rt][5][i]) << 16);
        pk.w = (unsigned)f2bf(acc[rt][6][i]) | ((unsigned)f2bf(acc[rt][7][i]) << 16);
        *(uint4*)&O[(size_t)row * FDIM + l15 * 8] = pk;
      }
    }
  }
}

// ---------------- aggregation (pull) + bias + ReLU ------------------------
// 2 nodes per wave: 32 lanes x uint2 (8 B) = 256 B row; colPacked 4 B/edge.
// POOL=1 (layer 3): skip Hout, reduce relu'd fp32 rows into a REPLICATED
// accumulator pooledR[blockIdx&31][graph][128]. R13's single copy serialized
// 1.6M atomics on 512 lines (~78 us); 32 replicas cut per-line contention
// 32x. k_final sums the replicas.
template <int POOL>
__global__ __launch_bounds__(256) void k_agg(const ushort_t* __restrict__ Hin,
                                             ushort_t* __restrict__ Hout,
                                             const int* __restrict__ rowStart,
                                             const int* __restrict__ degE,
                                             const unsigned* __restrict__ colPacked,
                                             const float* __restrict__ dis,
                                             const float* __restrict__ bias, int n,
                                             const int* __restrict__ batch,
                                             float* __restrict__ pooledR,
                                             int g_count) {
  __shared__ float pbuf[FDIM];
  __shared__ int guni;
  int t = threadIdx.x;
  int node = blockIdx.x * 8 + (t >> 5);
  int lane = t & 31;  // uint2 index within the 256 B row
  if (POOL) {
    if (t < FDIM) pbuf[t] = 0.f;
    if (t == 0) {
      int nb0 = blockIdx.x * 8;
      int nlast = min(nb0 + 7, n - 1);
      int g0 = batch[nb0];
      guni = (batch[nlast] == g0) ? g0 : -1;
    }
    __syncthreads();
  }
  bool active = node < n;
  float a0 = 0.f, a1 = 0.f, a2 = 0.f, a3 = 0.f;
  if (active) {
    const uint2* hin = (const uint2*)Hin;  // row stride 32 uint2
    float di = dis[node];
    uint2 su = hin[(size_t)node * 32 + lane];
    float wsl = di * di;
    a0 = wsl * __uint_as_float(su.x << 16);
    a1 = wsl * __uint_as_float(su.x & 0xffff0000u);
    a2 = wsl * __uint_as_float(su.y << 16);
    a3 = wsl * __uint_as_float(su.y & 0xffff0000u);
    int s0 = rowStart[node], cnt = degE[node];
#pragma unroll 4
    for (int j = 0; j < cnt; ++j) {
      unsigned pv = colPacked[s0 + j];
      int sidx = (int)(pv & 0x1ffffu);
      float wv = di * __uint_as_float((pv >> 17) << 16);
      uint2 u = hin[(size_t)sidx * 32 + lane];
      a0 += wv * __uint_as_float(u.x << 16);
      a1 += wv * __uint_as_float(u.x & 0xffff0000u);
      a2 += wv * __uint_as_float(u.y << 16);
      a3 += wv * __uint_as_float(u.y & 0xffff0000u);
    }
    float4 b = ((const float4*)bias)[lane];
    a0 = fmaxf(a0 + b.x, 0.f);
    a1 = fmaxf(a1 + b.y, 0.f);
    a2 = fmaxf(a2 + b.z, 0.f);
    a3 = fmaxf(a3 + b.w, 0.f);
  }
  if (!POOL) {
    if (active) {
      uint2 o;
      o.x = (unsigned)f2bf(a0) | ((unsigned)f2bf(a1) << 16);
      o.y = (unsigned)f2bf(a2) | ((unsigned)f2bf(a3) << 16);
      ((uint2*)Hout)[(size_t)node * 32 + lane] = o;
    }
    return;
  }
  // POOL epilogue (replicated accumulator)
  float* rep = pooledR + (size_t)(blockIdx.x & (NREP - 1)) * g_count * FDIM;
  if (active) {
    if (guni >= 0) {
      atomicAdd(&pbuf[lane * 4 + 0], a0);
      atomicAdd(&pbuf[lane * 4 + 1], a1);
      atomicAdd(&pbuf[lane * 4 + 2], a2);
      atomicAdd(&pbuf[lane * 4 + 3], a3);
    } else {
      int g = batch[node];
      atomicAdd(&rep[(size_t)g * FDIM + lane * 4 + 0], a0);
      atomicAdd(&rep[(size_t)g * FDIM + lane * 4 + 1], a1);
      atomicAdd(&rep[(size_t)g * FDIM + lane * 4 + 2], a2);
      atomicAdd(&rep[(size_t)g * FDIM + lane * 4 + 3], a3);
    }
  }
  __syncthreads();
  if (guni >= 0 && t < FDIM) atomicAdd(&rep[(size_t)guni * FDIM + t], pbuf[t]);
}

// ---------------- classifier ----------------

__device__ inline int lower_bound_batch(const int* __restrict__ batch, int n, int g) {
  int lo = 0, hi = n;
  while (lo < hi) {
    int mid = (lo + hi) >> 1;
    if (batch[mid] < g) lo = mid + 1;
    else hi = mid;
  }
  return lo;
}

// One block per graph: sum replicas, mean, classify via wave shuffles.
__global__ __launch_bounds__(128) void k_final(const float* __restrict__ pooledR,
                                               const int* __restrict__ batch, int n,
                                               const float* __restrict__ Wc,
                                               const float* __restrict__ bc,
                                               float* __restrict__ out, int g_count) {
  __shared__ int se[2];
  __shared__ float red[6];  // 2 waves x 3 classes
  int t = threadIdx.x;
  int g = blockIdx.x;
  if (t < 2) se[t] = lower_bound_batch(batch, n, g + t);
  __syncthreads();
  float inv = 1.0f / (float)max(se[1] - se[0], 1);
  float s = 0.f;
#pragma unroll
  for (int r = 0; r < NREP; ++r)
    s += pooledR[((size_t)r * g_count + g) * FDIM + t];
  s *= inv;
#pragma unroll
  for (int c = 0; c < 3; ++c) {
    float v = s * Wc[t * 3 + c];
#pragma unroll
    for (int off = 1; off < 64; off <<= 1) v += __shfl_xor(v, off);
    if ((t & 63) == 0) red[(t >> 6) * 3 + c] = v;
  }
  __syncthreads();
  if (t < 3) out[g * 3 + t] = red[t] + red[3 + t] + bc[t];
}

// ---------------- host ----------------

extern "C" void kernel_launch(void* const* d_in, const int* in_sizes, int n_in,
                              void* d_out, int out_size, void* d_ws, size_t ws_size,
                              hipStream_t stream) {
  const float* x = (const float*)d_in[0];
  const int* edge = (const int*)d_in[1];
  const int* batch = (const int*)d_in[2];
  const float* W1 = (const float*)d_in[3];
  const float* b1 = (const float*)d_in[4];
  const float* W2 = (const float*)d_in[5];
  const float* b2 = (const float*)d_in[6];
  const float* W3 = (const float*)d_in[7];
  const float* b3 = (const float*)d_in[8];
  const float* Wc = (const float*)d_in[9];
  const float* bc = (const float*)d_in[10];
  float* out = (float*)d_out;

  const int N = in_sizes[0] / FDIM;
  const int E = in_sizes[1] / 2;
  const int G = out_size / 3;
  const int* src = edge;
  const int* dst = edge + E;

  const int NCH = (E + CHUNK - 1) / CHUNK;
  const int NB = (N + (1 << BSHIFT) - 1) >> BSHIFT;

  char* ws = (char*)d_ws;
  size_t off = 0;
  auto carve = [&](size_t bytes) -> void* {
    void* p = ws + off;
    off = (off + bytes + 255) & ~(size_t)255;
    return p;
  };
  ushort_t* h0 = (ushort_t*)carve((size_t)N * FDIM * 2);  // row-major bf16
  ushort_t* h1 = (ushort_t*)carve((size_t)N * FDIM * 2);
  unsigned* colPacked = (unsigned*)carve((size_t)E * 4);
  unsigned* binned = (unsigned*)carve((size_t)E * 4);
  int* chunkHist = (int*)carve((size_t)NCH * NB * 4);
  int* chunkOff = (int*)carve((size_t)NCH * NB * 4);
  int* bucketTotal = (int*)carve((size_t)NB * 4);
  int* bucketBase = (int*)carve((size_t)NB * 4);
  int* counter = (int*)carve(256);
  int* rowStart = (int*)carve((size_t)N * 4);
  int* deg = (int*)carve((size_t)N * 4);
  float* dis = (float*)carve((size_t)N * 4);
  float* pooledR = (float*)carve((size_t)NREP * G * FDIM * 4);  // 1 MB
  ushort_t* wsw = (ushort_t*)carve((size_t)3 * 16384 * 2);  // swizzled bf16 W
  (void)n_in;
  (void)ws_size;

  hipMemsetAsync(pooledR, 0, (size_t)NREP * G * FDIM * 4, stream);

  k_histw<<<NCH + 3, 256, 0, stream>>>(dst, E, NB, chunkHist, NCH, W1, W2, W3, wsw,
                                       counter);
  k_scan1<<<NB, 512, 0, stream>>>(chunkHist, NCH, NB, chunkOff, bucketTotal,
                                  bucketBase, counter);
  k_bin<<<NCH, 256, 0, stream>>>(src, dst, E, NB, chunkHist, chunkOff, bucketBase,
                                 binned);
  k_fill2<<<NB, 256, 0, stream>>>(binned, bucketBase, bucketTotal, N, rowStart, deg,
                                  dis, colPacked);

  int mmb = (N + 127) / 128;
  int ewb = (E + 2047) / 2048;
  int aggb = (N + 7) / 8;
  k_mm<0, 1><<<mmb + ewb, 256, 0, stream>>>(x, wsw, h0, N, mmb, colPacked, E, dis);
  k_agg<0><<<aggb, 256, 0, stream>>>(h0, h1, rowStart, deg, colPacked, dis, b1, N,
                                     batch, nullptr, G);
  k_mm<1, 0><<<mmb, 256, 0, stream>>>(h1, wsw + 16384, h0, N, mmb, nullptr, 0,
                                      nullptr);
  k_agg<0><<<aggb, 256, 0, stream>>>(h0, h1, rowStart, deg, colPacked, dis, b2, N,
                                     batch, nullptr, G);
  k_mm<1, 0><<<mmb, 256, 0, stream>>>(h1, wsw + 32768, h0, N, mmb, nullptr, 0,
                                      nullptr);
  k_agg<1><<<aggb, 256, 0, stream>>>(h0, h1, rowStart, deg, colPacked, dis, b3, N,
                                     batch, pooledR, G);

  k_final<<<G, 128, 0, stream>>>(pooledR, batch, N, Wc, bc, out, G);
}